// Round 15
// baseline (394.026 us; speedup 1.0000x reference)
//
#include <hip/hip_runtime.h>

typedef unsigned short u16;
typedef __attribute__((ext_vector_type(8))) short short8;
typedef __attribute__((ext_vector_type(8))) _Float16 half8;
typedef __attribute__((ext_vector_type(4))) float f32x4;
typedef __attribute__((ext_vector_type(4))) u16 u16x4;
typedef __attribute__((ext_vector_type(4))) unsigned int u32x4;

#define DEVINL static __device__ __forceinline__

DEVINL u16 f2bf(float f) {
  unsigned u = __builtin_bit_cast(unsigned, f);
  u += 0x7fffu + ((u >> 16) & 1u);
  return (u16)(u >> 16);
}
DEVINL float bf2f(u16 h) {
  return __builtin_bit_cast(float, ((unsigned)h) << 16);
}
DEVINL u16 f2h(float f) { return __builtin_bit_cast(u16, (_Float16)f); }
DEVINL float h2f(u16 h) { return (float)__builtin_bit_cast(_Float16, h); }

// async global->LDS, 16B per lane; lds base must be wave-uniform
DEVINL void gload16(const void* g, void* l) {
  __builtin_amdgcn_global_load_lds(
      (const __attribute__((address_space(1))) void*)g,
      (__attribute__((address_space(3))) void*)l, 16, 0, 0);
}

#define BAR() asm volatile("s_barrier" ::: "memory")
#define WAIT_VMN(n) asm volatile("s_waitcnt vmcnt(" #n ")" ::: "memory")
#define WAIT_VM_LGKM0() asm volatile("s_waitcnt vmcnt(0) lgkmcnt(0)" ::: "memory")

// ---------------- standalone converts ----------------

// K_w [j=1024][h=1024] f32 -> transposed single fp16: out[h][j]
// (separate launch BEFORE front_k: qp reads kwT)
__global__ __launch_bounds__(256) void cvt_w_t_h_k(const float* __restrict__ in,
                                                   u16* __restrict__ out) {
  __shared__ float tile[64][65];
  const int bh = blockIdx.x * 64;
  const int bj = blockIdx.y * 64;
  const int t = threadIdx.x;
  const int r = t >> 4;
  const int c4 = (t & 15) * 4;
#pragma unroll
  for (int it = 0; it < 4; ++it) {
    const int row = it * 16 + r;
    const f32x4 v = *(const f32x4*)(in + (size_t)(bj + row) * 1024 + bh + c4);
#pragma unroll
    for (int j = 0; j < 4; ++j) tile[c4 + j][row] = v[j];
  }
  __syncthreads();
#pragma unroll
  for (int it = 0; it < 4; ++it) {
    const int hrow = it * 16 + r;
    u16x4 of;
#pragma unroll
    for (int j = 0; j < 4; ++j) of[j] = f2h(tile[hrow][c4 + j]);
    *(u16x4*)(out + (size_t)(bh + hrow) * 1024 + bj + c4) = of;
  }
}

// ---------------- front_k: heterogeneous fusion ----------------
// Roles by blockIdx (grid 4864):
//   bid<1024: even -> qp block (qid=bid>>1, 512 total), odd -> cvt_hidden (cid=bid>>1)
//   1024<=bid<4608: cvt_hidden (cid = 512 + bid-1024; 4096 total)
//   4608<=bid<4864: V_w -> bf16 grid-stride
// Shared 80KB (union): qp uses lA 2x16384 u16 + lB 2x4096 u16; cvt uses tl[64][136].
// 80KB -> 2 blocks/CU: one qp + one cvt co-resident (m114: MFMA & streaming waves overlap).
//
// qp: q' = x @ kwT^T. 256Mx128N tile, BK=32, 8 waves (2x4), wave tile 128x32.
// x read f32, split fp16 hi/lo in-register, b128 ds_write into swizzled pair layout
// (row r chunk c holds global g=c^(r&7); g<4 hi k-chunk g, else lo). fp16-split out.
__global__ __launch_bounds__(512) void front_k(
    const float* __restrict__ hid, const float* __restrict__ X,
    const u16* __restrict__ kwT, const float* __restrict__ Vw,
    u16* __restrict__ hf, u16* __restrict__ hT, u16* __restrict__ vw,
    u16* __restrict__ Chi, u16* __restrict__ Clo) {
  __shared__ u16 smem[40960];  // 80 KiB
  const int bid = blockIdx.x;
  const int tid = threadIdx.x;

  if (bid < 1024 && (bid & 1) == 0) {
    // ================= qp GEMM =================
    const int qid = bid >> 1;
    const int swz = (qid & 7) * 64 + (qid >> 3);  // bijective on 512
    const int m0 = (swz >> 3) * 256;
    const int n0 = (swz & 7) * 128;
    const int lane = tid & 63, wid = tid >> 6;
    const int wr = wid >> 2, wc = wid & 3;  // wave tile 128x32
    const int fr = lane & 15, fk = lane >> 4;

    f32x4 acc[8][2] = {};

    // A fused stage: 1024 (hi,lo) slot-pairs over 256 rows x 4 q; b128 stores.
#define STAGEAF(pb, kt)                                                        \
  {                                                                            \
    _Pragma("unroll") for (int j = 0; j < 2; ++j) {                            \
      const int ps = j * 512 + tid;                                            \
      const int r = ps >> 2, q = ps & 3;                                       \
      const float* src = X + (size_t)(m0 + r) * 1024 + (kt) * 32 + q * 8;      \
      const f32x4 v0 = *(const f32x4*)src;                                     \
      const f32x4 v1 = *(const f32x4*)(src + 4);                               \
      short8 hs, ls;                                                           \
      _Pragma("unroll") for (int e = 0; e < 4; ++e) {                          \
        const u16 a0 = f2h(v0[e]);                                             \
        const u16 a1 = f2h(v1[e]);                                             \
        hs[e] = (short)a0;                                                     \
        hs[e + 4] = (short)a1;                                                 \
        ls[e] = (short)f2h(v0[e] - h2f(a0));                                   \
        ls[e + 4] = (short)f2h(v1[e] - h2f(a1));                               \
      }                                                                        \
      const int c = q ^ (r & 7);                                               \
      *(short8*)&smem[(pb) * 16384 + r * 64 + c * 8] = hs;                     \
      *(short8*)&smem[(pb) * 16384 + r * 64 + (c ^ 4) * 8] = ls;               \
    }                                                                          \
  }
    // B K-tile: 128 rows x 32 k fp16, 1 gload per thread
#define STAGEB(pb, kt)                                                         \
  {                                                                            \
    const int slot = tid;                                                      \
    const int r = slot >> 2;                                                   \
    const int g = (slot & 3) ^ ((r >> 1) & 3);                                 \
    gload16(kwT + (size_t)(n0 + r) * 1024 + (kt) * 32 + g * 8,                 \
            &smem[32768 + (pb) * 4096 + (wid * 64) * 8]);                      \
  }

    STAGEAF(0, 0);
    STAGEB(0, 0);

    for (int t = 0; t < 32; ++t) {
      const int p = t & 1;
      WAIT_VM_LGKM0();
      BAR();
      half8 bf[2];
#pragma unroll
      for (int nf = 0; nf < 2; ++nf) {
        const int rn = wc * 32 + nf * 16 + fr;
        const int cn = fk ^ ((rn >> 1) & 3);
        bf[nf] = *(const half8*)&smem[32768 + p * 4096 + rn * 32 + cn * 8];
      }
      if (t < 31) {
        STAGEB(p ^ 1, t + 1);
        STAGEAF(p ^ 1, t + 1);
      }
#pragma unroll
      for (int ph = 0; ph < 4; ++ph) {
        half8 ah[2], al[2];
#pragma unroll
        for (int i = 0; i < 2; ++i) {
          const int r = wr * 128 + (ph * 2 + i) * 16 + fr;
          const int ch = fk ^ (r & 7);
          ah[i] = *(const half8*)&smem[p * 16384 + r * 64 + ch * 8];
          al[i] = *(const half8*)&smem[p * 16384 + r * 64 + (ch ^ 4) * 8];
        }
        __builtin_amdgcn_s_setprio(1);
#pragma unroll
        for (int i = 0; i < 2; ++i)
#pragma unroll
          for (int nf = 0; nf < 2; ++nf) {
            acc[ph * 2 + i][nf] = __builtin_amdgcn_mfma_f32_16x16x32_f16(
                ah[i], bf[nf], acc[ph * 2 + i][nf], 0, 0, 0);
            acc[ph * 2 + i][nf] = __builtin_amdgcn_mfma_f32_16x16x32_f16(
                al[i], bf[nf], acc[ph * 2 + i][nf], 0, 0, 0);
          }
        __builtin_amdgcn_s_setprio(0);
      }
    }
#undef STAGEAF
#undef STAGEB

    const int cb = n0 + wc * 32 + fr;
    const int rb = m0 + wr * 128 + fk * 4;
#pragma unroll
    for (int mf = 0; mf < 8; ++mf)
#pragma unroll
      for (int nf = 0; nf < 2; ++nf) {
        const int col = cb + nf * 16;
#pragma unroll
        for (int j = 0; j < 4; ++j) {
          const int row = rb + mf * 16 + j;
          const float kv = acc[mf][nf][j];
          const u16 hi = f2h(kv);
          Chi[(size_t)row * 1024 + col] = hi;
          Clo[(size_t)row * 1024 + col] = f2h(kv - h2f(hi));
        }
      }
  } else if (bid < 4608) {
    // ================= cvt_hidden =================
    const int cid = (bid < 1024) ? (bid >> 1) : (512 + (bid - 1024));
    const int s0 = (cid & 15) * 64;
    const int h0 = ((cid >> 4) & 7) * 128;
    const int b = cid >> 7;
    u16(*tl)[136] = (u16(*)[136])smem;
    const int r = tid >> 5;         // 0..15
    const int c4 = (tid & 31) * 4;  // 0..124
#pragma unroll
    for (int it = 0; it < 4; ++it) {
      const int s = it * 16 + r;
      const f32x4 v = *(const f32x4*)(hid + ((size_t)(s0 + s) * 32 + b) * 1024 + h0 + c4);
      u16x4 of;
      const int cs = c4 ^ (it << 2);
#pragma unroll
      for (int j = 0; j < 4; ++j) {
        of[j] = f2h(v[j]);
        tl[s][cs + j] = f2bf(v[j]);
      }
      *(u16x4*)(hf + ((size_t)b * 1024 + s0 + s) * 1024 + h0 + c4) = of;
    }
    __syncthreads();
    const int h = tid >> 2;  // 0..127
    const int sq = (tid & 3) * 16;
    u16 tmp[16] __attribute__((aligned(16)));
#pragma unroll
    for (int i = 0; i < 16; ++i)
      tmp[i] = tl[sq + i][h ^ ((((sq + i) >> 4) & 3) << 2)];
    u16* dst = hT + ((size_t)b * 1024 + h0 + h) * 1024 + s0 + sq;
    *(u32x4*)(dst) = *(const u32x4*)&tmp[0];
    *(u32x4*)(dst + 8) = *(const u32x4*)&tmp[8];
  } else {
    // ================= V_w -> bf16 =================
    long i = (long)(bid - 4608) * 512 + tid;
    for (; i < 262144; i += 131072) {
      const f32x4 v = ((const f32x4*)Vw)[i];
      u16x4 o;
#pragma unroll
      for (int j = 0; j < 4; ++j) o[j] = f2bf(v[j]);
      ((u16x4*)vw)[i] = o;
    }
  }
}

// ---------------- scores: 2-pass fp16 GEMM, 3-deep, counted vmcnt ----------------
// scores[b] = (Qh+Ql)[b] @ Hf[b]^T, batched B=32, f32 out.
__global__ __launch_bounds__(512) void gemm_sc_k(
    const u16* __restrict__ Qh_, const u16* __restrict__ Ql_,
    const u16* __restrict__ Hf_, float* __restrict__ S) {
  __shared__ u16 lA[3][256 * 64];  // 96 KiB
  __shared__ u16 lB[3][256 * 32];  // 48 KiB
  const int bid = blockIdx.x;
  const int swz = (bid & 7) * 32 + (bid >> 3);
  const int z = swz >> 3;
  const int m0 = ((swz >> 2) & 1) * 256;
  const int n0 = (swz & 3) * 256;
  const u16* Ah = Qh_ + (size_t)z * 512 * 1024;
  const u16* Al = Ql_ + (size_t)z * 512 * 1024;
  const u16* Bm = Hf_ + (size_t)z * 1024 * 1024;
  float* Cf = S + (size_t)z * 512 * 1024;
  const int tid = threadIdx.x;
  const int lane = tid & 63, wid = tid >> 6;
  const int wr = wid >> 2, wc = wid & 3;
  const int fr = lane & 15, fk = lane >> 4;

  f32x4 acc[8][4] = {};

#define STAGEA(pb, kt)                                                         \
  {                                                                            \
    _Pragma("unroll") for (int j = 0; j < 4; ++j) {                            \
      const int slot = j * 512 + tid;                                          \
      const int r = slot >> 3;                                                 \
      const int g = (slot & 7) ^ (r & 7);                                      \
      const u16* src = (g < 4) ? Ah : Al;                                      \
      gload16(src + (size_t)(m0 + r) * 1024 + (kt) * 32 + (g & 3) * 8,         \
              &lA[pb][(j * 512 + wid * 64) * 8]);                              \
    }                                                                          \
  }
#define STAGEB(pb, kt)                                                         \
  {                                                                            \
    _Pragma("unroll") for (int j = 0; j < 2; ++j) {                            \
      const int slot = j * 512 + tid;                                          \
      const int r = slot >> 2;                                                 \
      const int g = (slot & 3) ^ ((r >> 1) & 3);                               \
      gload16(Bm + (size_t)(n0 + r) * 1024 + (kt) * 32 + g * 8,                \
              &lB[pb][(j * 512 + wid * 64) * 8]);                              \
    }                                                                          \
  }

  STAGEA(0, 0);
  STAGEB(0, 0);
  STAGEA(1, 1);
  STAGEB(1, 1);

  int cur = 0;
  for (int t = 0; t < 32; ++t) {
    if (t < 31) {
      WAIT_VMN(6);
    } else {
      WAIT_VMN(0);
    }
    BAR();
    int pre = cur + 2;
    if (pre >= 3) pre -= 3;
    half8 bf[4];
#pragma unroll
    for (int nf = 0; nf < 4; ++nf) {
      const int rn = wc * 64 + nf * 16 + fr;
      const int cn = fk ^ ((rn >> 1) & 3);
      bf[nf] = *(const half8*)&lB[cur][rn * 32 + cn * 8];
    }
    if (t < 30) {
      STAGEA(pre, t + 2);
      STAGEB(pre, t + 2);
    }
#pragma unroll
    for (int ph = 0; ph < 4; ++ph) {
      half8 ah[2], al[2];
#pragma unroll
      for (int i = 0; i < 2; ++i) {
        const int r = wr * 128 + (ph * 2 + i) * 16 + fr;
        const int ch = fk ^ (r & 7);
        ah[i] = *(const half8*)&lA[cur][r * 64 + ch * 8];
        al[i] = *(const half8*)&lA[cur][r * 64 + (ch ^ 4) * 8];
      }
      __builtin_amdgcn_s_setprio(1);
#pragma unroll
      for (int i = 0; i < 2; ++i)
#pragma unroll
        for (int nf = 0; nf < 4; ++nf) {
          acc[ph * 2 + i][nf] =
              __builtin_amdgcn_mfma_f32_16x16x32_f16(ah[i], bf[nf], acc[ph * 2 + i][nf], 0, 0, 0);
          acc[ph * 2 + i][nf] =
              __builtin_amdgcn_mfma_f32_16x16x32_f16(al[i], bf[nf], acc[ph * 2 + i][nf], 0, 0, 0);
        }
      __builtin_amdgcn_s_setprio(0);
    }
    ++cur;
    if (cur == 3) cur = 0;
  }
#undef STAGEA
#undef STAGEB

  const int cb = n0 + wc * 64 + fr;
  const int rb = m0 + wr * 128 + fk * 4;
#pragma unroll
  for (int mf = 0; mf < 8; ++mf)
#pragma unroll
    for (int nf = 0; nf < 4; ++nf) {
      const int col = cb + nf * 16;
#pragma unroll
      for (int j = 0; j < 4; ++j) {
        const int row = rb + mf * 16 + j;
        Cf[(size_t)row * 1024 + col] = acc[mf][nf][j];
      }
    }
}

// ---------------- single-pass bf16 GEMM, 2-buf, 1 barrier per K-tile ----------------
// CM 0: ctx = attn[b] @ hT[b]^T, batched, bf16 out.
// CM 1: out = sigmoid(A @ Bt^T + bias), flat M=16384, f32 out.
template <int CM>
__global__ __launch_bounds__(512) void gemm1_8ph_k(
    const u16* __restrict__ A_, const u16* __restrict__ Bt_,
    const float* __restrict__ bias, void* __restrict__ Cout) {
  __shared__ u16 lds[2][2][256 * 64];  // 131072 B
  const int bid = blockIdx.x;
  const int swz = (bid & 7) * 32 + (bid >> 3);
  int m0, n0;
  const u16 *A, *Bt;
  float* Cf = nullptr;
  u16* Cb = nullptr;
  if (CM == 0) {
    const int z = swz >> 3;
    m0 = ((swz >> 2) & 1) * 256;
    n0 = (swz & 3) * 256;
    A = A_ + (size_t)z * 512 * 1024;
    Bt = Bt_ + (size_t)z * 1024 * 1024;
    Cb = (u16*)Cout + (size_t)z * 512 * 1024;
  } else {
    m0 = (swz >> 2) * 256;
    n0 = (swz & 3) * 256;
    A = A_; Bt = Bt_;
    Cf = (float*)Cout;
  }
  const int tid = threadIdx.x;
  const int lane = tid & 63, wid = tid >> 6;
  const int wr = wid >> 2, wc = wid & 3;
  const int fr = lane & 15, fk = lane >> 4;

  f32x4 acc[8][4] = {};

#define STAGE1(pb, q, gp, rb, kt)                                              \
  {                                                                            \
    _Pragma("unroll") for (int j = 0; j < 4; ++j) {                            \
      const int slot = j * 512 + tid;                                          \
      const int r = slot >> 3;                                                 \
      const int g = (slot & 7) ^ (r & 7);                                      \
      gload16((gp) + (size_t)((rb) + r) * 1024 + (kt) * 64 + g * 8,            \
              &lds[pb][q][(j * 512 + wid * 64) * 8]);                          \
    }                                                                          \
  }

  STAGE1(0, 0, A, m0, 0);
  STAGE1(0, 1, Bt, n0, 0);

  for (int t = 0; t < 16; ++t) {
    const int p = t & 1;
    WAIT_VMN(0);
    BAR();
    short8 bfr[4][2];
#pragma unroll
    for (int nf = 0; nf < 4; ++nf) {
      const int rn = wc * 64 + nf * 16 + fr;
#pragma unroll
      for (int ks = 0; ks < 2; ++ks) {
        const int g = (ks * 4 + fk) ^ (rn & 7);
        bfr[nf][ks] = *(const short8*)&lds[p][1][rn * 64 + g * 8];
      }
    }
    if (t < 15) {
      STAGE1(p ^ 1, 0, A, m0, t + 1);
      STAGE1(p ^ 1, 1, Bt, n0, t + 1);
    }
#pragma unroll
    for (int ph = 0; ph < 4; ++ph) {
      short8 a[2][2];
#pragma unroll
      for (int i = 0; i < 2; ++i) {
        const int r = wr * 128 + (ph * 2 + i) * 16 + fr;
#pragma unroll
        for (int ks = 0; ks < 2; ++ks) {
          const int g = (ks * 4 + fk) ^ (r & 7);
          a[i][ks] = *(const short8*)&lds[p][0][r * 64 + g * 8];
        }
      }
      __builtin_amdgcn_s_setprio(1);
#pragma unroll
      for (int i = 0; i < 2; ++i)
#pragma unroll
        for (int nf = 0; nf < 4; ++nf) {
          acc[ph * 2 + i][nf] = __builtin_amdgcn_mfma_f32_16x16x32_bf16(
              a[i][0], bfr[nf][0], acc[ph * 2 + i][nf], 0, 0, 0);
          acc[ph * 2 + i][nf] = __builtin_amdgcn_mfma_f32_16x16x32_bf16(
              a[i][1], bfr[nf][1], acc[ph * 2 + i][nf], 0, 0, 0);
        }
      __builtin_amdgcn_s_setprio(0);
    }
  }
#undef STAGE1

  const int cb = n0 + wc * 64 + fr;
  const int rb = m0 + wr * 128 + fk * 4;
  if (CM == 0) {
#pragma unroll
    for (int mf = 0; mf < 8; ++mf)
#pragma unroll
      for (int nf = 0; nf < 4; ++nf) {
        const int col = cb + nf * 16;
#pragma unroll
        for (int j = 0; j < 4; ++j) {
          const int row = rb + mf * 16 + j;
          Cb[(size_t)row * 1024 + col] = f2bf(acc[mf][nf][j]);
        }
      }
  } else {
#pragma unroll
    for (int mf = 0; mf < 8; ++mf)
#pragma unroll
      for (int nf = 0; nf < 4; ++nf) {
        const int col = cb + nf * 16;
        const float bv = bias[col];
#pragma unroll
        for (int j = 0; j < 4; ++j) {
          const int row = rb + mf * 16 + j;
          const float xv = acc[mf][nf][j] + bv;
          Cf[(size_t)row * 1024 + col] = 1.0f / (1.0f + __expf(-xv));
        }
      }
  }
}

// ---------------- softmax over last dim (1024), writes compact bf16 attn ----------------
__global__ __launch_bounds__(256) void softmax_k(const float* __restrict__ S,
                                                 u16* __restrict__ Attn) {
  const float* rp = S + (size_t)blockIdx.x * 1024;
  const int tid = threadIdx.x;
  const int lane = tid & 63, wid = tid >> 6;
  const f32x4 v = ((const f32x4*)rp)[tid];
  float mx = fmaxf(fmaxf(v[0], v[1]), fmaxf(v[2], v[3]));
#pragma unroll
  for (int off = 32; off; off >>= 1) mx = fmaxf(mx, __shfl_xor(mx, off));
  __shared__ float red[4];
  __shared__ float red2[4];
  if (lane == 0) red[wid] = mx;
  __syncthreads();
  mx = fmaxf(fmaxf(red[0], red[1]), fmaxf(red[2], red[3]));
  const float e0 = __expf(v[0] - mx), e1 = __expf(v[1] - mx);
  const float e2 = __expf(v[2] - mx), e3 = __expf(v[3] - mx);
  float s = (e0 + e1) + (e2 + e3);
#pragma unroll
  for (int off = 32; off; off >>= 1) s += __shfl_xor(s, off);
  if (lane == 0) red2[wid] = s;
  __syncthreads();
  const float inv = 1.0f / (red2[0] + red2[1] + red2[2] + red2[3]);
  u16x4 o;
  o[0] = f2bf(e0 * inv); o[1] = f2bf(e1 * inv); o[2] = f2bf(e2 * inv); o[3] = f2bf(e3 * inv);
  ((u16x4*)(Attn + (size_t)blockIdx.x * 1024))[tid] = o;
}

// ---------------- launch ----------------
// Shapes: S=1024, B=32, H=1024, T=512.
//   kwT = K_w^T fp16          (3µs, must precede front_k)
//   front_k: qp (fused x-split fp16 GEMM) || cvt_hidden || vw-cvt  (heterogeneous blocks)
//   scr = q'[b] @ hf16[b]^T   (fp16 2-pass, 3-buf counted-vmcnt)
//   attn = softmax(scr)       (compact bf16)
//   ctx = attn[b] @ hT[b]^T   (bf16, 2-buf)
//   out = sigmoid(ctx @ V_w^T + V_b)
// ws (MB): hf16 0-64 (attn reuses 0-32) | hT 64-128 | qhi 128-160 (ctx reuses) |
//          qlo 160-192 | scores f32 192-256 | kwT 256-258 | vw 258-260
extern "C" void kernel_launch(void* const* d_in, const int* in_sizes, int n_in,
                              void* d_out, int out_size, void* d_ws, size_t ws_size,
                              hipStream_t stream) {
  const float* hidden = (const float*)d_in[0];
  const float* x = (const float*)d_in[1];
  // d_in[2] problem_q unused; d_in[4] K_b dropped (softmax shift invariance)
  const float* K_w = (const float*)d_in[3];
  const float* V_w = (const float*)d_in[5];
  const float* V_b = (const float*)d_in[6];

  char* ws = (char*)d_ws;
  u16* hf16 = (u16*)(ws);
  u16* hT = (u16*)(ws + 67108864);
  u16* qhi = (u16*)(ws + 134217728);
  u16* qlo = (u16*)(ws + 167772160);
  float* scoresF = (float*)(ws + 201326592);
  u16* attn = hf16;  // reuse (hf16 dead after scores)
  u16* ctx = qhi;    // reuse (q' dead after scores)
  u16* kwT = (u16*)(ws + 268435456);
  u16* vw = kwT + 1024 * 1024;
  float* out = (float*)d_out;

  // 1. K_w -> transposed fp16 (qp input; separate launch = dependency barrier)
  cvt_w_t_h_k<<<dim3(16, 16), 256, 0, stream>>>(K_w, kwT);
  // 2. front: qp GEMM + hidden converts + V_w convert, co-scheduled
  front_k<<<4864, 512, 0, stream>>>(hidden, x, kwT, V_w, hf16, hT, vw, qhi, qlo);
  // 3. scores[b] = q'[b] @ hf16[b]^T
  gemm_sc_k<<<256, 512, 0, stream>>>(qhi, qlo, hf16, scoresF);
  // 4. softmax over S -> compact bf16 attn
  softmax_k<<<16384, 256, 0, stream>>>(scoresF, attn);
  // 5. ctx[b] = attn[b] @ hT[b]^T
  gemm1_8ph_k<0><<<256, 512, 0, stream>>>(attn, hT, nullptr, ctx);
  // 6. out = sigmoid(ctx @ V_w^T + V_b)
  gemm1_8ph_k<1><<<256, 512, 0, stream>>>(ctx, vw, V_b, out);
}

// Round 16
// 335.091 us; speedup vs baseline: 1.1759x; 1.1759x over previous
//
#include <hip/hip_runtime.h>

typedef unsigned short u16;
typedef __attribute__((ext_vector_type(8))) short short8;
typedef __attribute__((ext_vector_type(8))) _Float16 half8;
typedef __attribute__((ext_vector_type(4))) float f32x4;
typedef __attribute__((ext_vector_type(4))) u16 u16x4;
typedef __attribute__((ext_vector_type(4))) unsigned int u32x4;

#define DEVINL static __device__ __forceinline__

DEVINL u16 f2bf(float f) {
  unsigned u = __builtin_bit_cast(unsigned, f);
  u += 0x7fffu + ((u >> 16) & 1u);
  return (u16)(u >> 16);
}
DEVINL float bf2f(u16 h) {
  return __builtin_bit_cast(float, ((unsigned)h) << 16);
}
DEVINL u16 f2h(float f) { return __builtin_bit_cast(u16, (_Float16)f); }
DEVINL float h2f(u16 h) { return (float)__builtin_bit_cast(_Float16, h); }

// async global->LDS, 16B per lane; lds base must be wave-uniform
DEVINL void gload16(const void* g, void* l) {
  __builtin_amdgcn_global_load_lds(
      (const __attribute__((address_space(1))) void*)g,
      (__attribute__((address_space(3))) void*)l, 16, 0, 0);
}

#define BAR() asm volatile("s_barrier" ::: "memory")
#define WAIT_VMN(n) asm volatile("s_waitcnt vmcnt(" #n ")" ::: "memory")
#define WAIT_VM_LGKM0() asm volatile("s_waitcnt vmcnt(0) lgkmcnt(0)" ::: "memory")

// ---------------- converts ----------------

// hidden [S=1024,B=32,H=1024] f32 -> hf16 [B,S,H] fp16 + hT [B,H,S] bf16
// 512 threads, 64s x 128h tile; XOR col-swizzled LDS transpose.
__global__ __launch_bounds__(512) void cvt_hidden2_k(const float* __restrict__ hid,
                                                     u16* __restrict__ hf,
                                                     u16* __restrict__ hT) {
  __shared__ u16 tl[64][136];
  const int s0 = blockIdx.x * 64;
  const int h0 = blockIdx.y * 128;
  const int b = blockIdx.z;
  const int t = threadIdx.x;
  const int r = t >> 5;
  const int c4 = (t & 31) * 4;
#pragma unroll
  for (int it = 0; it < 4; ++it) {
    const int s = it * 16 + r;
    const f32x4 v = *(const f32x4*)(hid + ((size_t)(s0 + s) * 32 + b) * 1024 + h0 + c4);
    u16x4 of;
    const int cs = c4 ^ (it << 2);
#pragma unroll
    for (int j = 0; j < 4; ++j) {
      of[j] = f2h(v[j]);
      tl[s][cs + j] = f2bf(v[j]);
    }
    *(u16x4*)(hf + ((size_t)b * 1024 + s0 + s) * 1024 + h0 + c4) = of;
  }
  __syncthreads();
  const int h = t >> 2;
  const int sq = (t & 3) * 16;
  u16 tmp[16] __attribute__((aligned(16)));
#pragma unroll
  for (int i = 0; i < 16; ++i)
    tmp[i] = tl[sq + i][h ^ ((((sq + i) >> 4) & 3) << 2)];
  u16* dst = hT + ((size_t)b * 1024 + h0 + h) * 1024 + s0 + sq;
  *(u32x4*)(dst) = *(const u32x4*)&tmp[0];
  *(u32x4*)(dst + 8) = *(const u32x4*)&tmp[8];
}

// generic f32 -> bf16 (single)
__global__ __launch_bounds__(256) void cvt_f32_bf16_k(const float* __restrict__ in,
                                                      u16* __restrict__ out, long n4) {
  long i = (long)blockIdx.x * 256 + threadIdx.x;
  const long stride = (long)gridDim.x * 256;
  for (; i < n4; i += stride) {
    const f32x4 v = ((const f32x4*)in)[i];
    u16x4 o;
#pragma unroll
    for (int j = 0; j < 4; ++j) o[j] = f2bf(v[j]);
    ((u16x4*)out)[i] = o;
  }
}

// K_w [j=1024][h=1024] f32 -> transposed single fp16: out[h][j]
__global__ __launch_bounds__(256) void cvt_w_t_h_k(const float* __restrict__ in,
                                                   u16* __restrict__ out) {
  __shared__ float tile[64][65];
  const int bh = blockIdx.x * 64;
  const int bj = blockIdx.y * 64;
  const int t = threadIdx.x;
  const int r = t >> 4;
  const int c4 = (t & 15) * 4;
#pragma unroll
  for (int it = 0; it < 4; ++it) {
    const int row = it * 16 + r;
    const f32x4 v = *(const f32x4*)(in + (size_t)(bj + row) * 1024 + bh + c4);
#pragma unroll
    for (int j = 0; j < 4; ++j) tile[c4 + j][row] = v[j];
  }
  __syncthreads();
#pragma unroll
  for (int it = 0; it < 4; ++it) {
    const int hrow = it * 16 + r;
    u16x4 of;
#pragma unroll
    for (int j = 0; j < 4; ++j) of[j] = f2h(tile[hrow][c4 + j]);
    *(u16x4*)(out + (size_t)(bh + hrow) * 1024 + bj + c4) = of;
  }
}

// ---------------- qp: fused-convert 2-pass fp16 GEMM (r14, 93us) ----------------
__global__ __launch_bounds__(512) void gemm_qp_k(
    const float* __restrict__ X, const u16* __restrict__ Bm,
    u16* __restrict__ Chi, u16* __restrict__ Clo) {
  __shared__ u16 lA[2][256 * 64];  // 64 KiB
  __shared__ u16 lB[2][256 * 32];  // 32 KiB
  const int bid = blockIdx.x;
  const int swz = (bid & 7) * 32 + (bid >> 3);
  const int m0 = (swz >> 2) * 256;
  const int n0 = (swz & 3) * 256;
  const int tid = threadIdx.x;
  const int lane = tid & 63, wid = tid >> 6;
  const int wr = wid >> 2, wc = wid & 3;
  const int fr = lane & 15, fk = lane >> 4;

  f32x4 acc[8][4] = {};

#define STAGEAF(pb, kt)                                                        \
  {                                                                            \
    _Pragma("unroll") for (int j = 0; j < 2; ++j) {                            \
      const int ps = j * 512 + tid;                                            \
      const int r = ps >> 2, q = ps & 3;                                       \
      const float* src = X + (size_t)(m0 + r) * 1024 + (kt) * 32 + q * 8;      \
      const f32x4 v0 = *(const f32x4*)src;                                     \
      const f32x4 v1 = *(const f32x4*)(src + 4);                               \
      short8 hs, ls;                                                           \
      _Pragma("unroll") for (int e = 0; e < 4; ++e) {                          \
        const u16 a0 = f2h(v0[e]);                                             \
        const u16 a1 = f2h(v1[e]);                                             \
        hs[e] = (short)a0;                                                     \
        hs[e + 4] = (short)a1;                                                 \
        ls[e] = (short)f2h(v0[e] - h2f(a0));                                   \
        ls[e + 4] = (short)f2h(v1[e] - h2f(a1));                               \
      }                                                                        \
      const int c = q ^ (r & 7);                                               \
      *(short8*)&lA[pb][r * 64 + c * 8] = hs;                                  \
      *(short8*)&lA[pb][r * 64 + (c ^ 4) * 8] = ls;                            \
    }                                                                          \
  }
#define STAGEB(pb, kt)                                                         \
  {                                                                            \
    _Pragma("unroll") for (int j = 0; j < 2; ++j) {                            \
      const int slot = j * 512 + tid;                                          \
      const int r = slot >> 2;                                                 \
      const int g = (slot & 3) ^ ((r >> 1) & 3);                               \
      gload16(Bm + (size_t)(n0 + r) * 1024 + (kt) * 32 + g * 8,                \
              &lB[pb][(j * 512 + wid * 64) * 8]);                              \
    }                                                                          \
  }

  STAGEAF(0, 0);
  STAGEB(0, 0);

  for (int t = 0; t < 32; ++t) {
    const int p = t & 1;
    WAIT_VM_LGKM0();
    BAR();
    half8 bf[4];
#pragma unroll
    for (int nf = 0; nf < 4; ++nf) {
      const int rn = wc * 64 + nf * 16 + fr;
      const int cn = fk ^ ((rn >> 1) & 3);
      bf[nf] = *(const half8*)&lB[p][rn * 32 + cn * 8];
    }
    if (t < 31) {
      STAGEB(p ^ 1, t + 1);
      STAGEAF(p ^ 1, t + 1);
    }
#pragma unroll
    for (int ph = 0; ph < 4; ++ph) {
      half8 ah[2], al[2];
#pragma unroll
      for (int i = 0; i < 2; ++i) {
        const int r = wr * 128 + (ph * 2 + i) * 16 + fr;
        const int ch = fk ^ (r & 7);
        ah[i] = *(const half8*)&lA[p][r * 64 + ch * 8];
        al[i] = *(const half8*)&lA[p][r * 64 + (ch ^ 4) * 8];
      }
      __builtin_amdgcn_s_setprio(1);
#pragma unroll
      for (int i = 0; i < 2; ++i)
#pragma unroll
        for (int nf = 0; nf < 4; ++nf) {
          acc[ph * 2 + i][nf] =
              __builtin_amdgcn_mfma_f32_16x16x32_f16(ah[i], bf[nf], acc[ph * 2 + i][nf], 0, 0, 0);
          acc[ph * 2 + i][nf] =
              __builtin_amdgcn_mfma_f32_16x16x32_f16(al[i], bf[nf], acc[ph * 2 + i][nf], 0, 0, 0);
        }
      __builtin_amdgcn_s_setprio(0);
    }
  }
#undef STAGEAF
#undef STAGEB

  const int cb = n0 + wc * 64 + fr;
  const int rb = m0 + wr * 128 + fk * 4;
#pragma unroll
  for (int mf = 0; mf < 8; ++mf)
#pragma unroll
    for (int nf = 0; nf < 4; ++nf) {
      const int col = cb + nf * 16;
#pragma unroll
      for (int j = 0; j < 4; ++j) {
        const int row = rb + mf * 16 + j;
        const float kv = acc[mf][nf][j];
        const u16 hi = f2h(kv);
        Chi[(size_t)row * 1024 + col] = hi;
        Clo[(size_t)row * 1024 + col] = f2h(kv - h2f(hi));
      }
    }
}

// ---------------- scores: 2-pass fp16 GEMM, BK=64, 16 boundaries ----------------
// scores[b] = (Qh+Ql)[b] @ Hf[b]^T. 128x256 tile, BK=64, 8 waves (2x4),
// wave tile 64x64, 2-buf 128KB LDS. Half the K-tile boundaries of BK=32
// (gemm1 same-family precedent: ~1000+ TF at BK=64 vs 827 at BK=32).
// A-pair rows 256B (16 chunks): chunk c holds global g = c^(r&7) (bit3 = hi/lo kept).
// B rows 128B (8 chunks): chunk c holds global g = c^(r&7). Reads 2-way (free).
__global__ __launch_bounds__(512) void gemm_sc_k(
    const u16* __restrict__ Qh_, const u16* __restrict__ Ql_,
    const u16* __restrict__ Hf_, float* __restrict__ S) {
  __shared__ u16 lA[2][128 * 128];  // 64 KiB
  __shared__ u16 lB[2][256 * 64];   // 64 KiB
  const int bid = blockIdx.x;
  const int swz = (bid & 7) * 64 + (bid >> 3);  // bijective on 512
  const int z = swz >> 4;
  const int m0 = ((swz >> 2) & 3) * 128;
  const int n0 = (swz & 3) * 256;
  const u16* Ah = Qh_ + (size_t)z * 512 * 1024;
  const u16* Al = Ql_ + (size_t)z * 512 * 1024;
  const u16* Bm = Hf_ + (size_t)z * 1024 * 1024;
  float* Cf = S + (size_t)z * 512 * 1024;
  const int tid = threadIdx.x;
  const int lane = tid & 63, wid = tid >> 6;
  const int wr = wid >> 2, wc = wid & 3;  // wave tile 64x64
  const int fr = lane & 15, fk = lane >> 4;

  f32x4 acc[4][4] = {};

  // A-pair: 128 rows x 16 chunks = 2048 slots, 4/thread
#define STAGEA(pb, kt)                                                         \
  {                                                                            \
    _Pragma("unroll") for (int j = 0; j < 4; ++j) {                            \
      const int slot = j * 512 + tid;                                          \
      const int r = slot >> 4;                                                 \
      const int g = (slot & 15) ^ (r & 7);                                     \
      const u16* src = (g < 8) ? Ah : Al;                                      \
      gload16(src + (size_t)(m0 + r) * 1024 + (kt) * 64 + (g & 7) * 8,         \
              &lA[pb][slot * 8]);                                              \
    }                                                                          \
  }
  // B: 256 rows x 8 chunks = 2048 slots, 4/thread
#define STAGEB(pb, kt)                                                         \
  {                                                                            \
    _Pragma("unroll") for (int j = 0; j < 4; ++j) {                            \
      const int slot = j * 512 + tid;                                          \
      const int r = slot >> 3;                                                 \
      const int g = (slot & 7) ^ (r & 7);                                      \
      gload16(Bm + (size_t)(n0 + r) * 1024 + (kt) * 64 + g * 8,                \
              &lB[pb][slot * 8]);                                              \
    }                                                                          \
  }

  STAGEA(0, 0);
  STAGEB(0, 0);

  for (int t = 0; t < 16; ++t) {
    const int p = t & 1;
    WAIT_VMN(0);
    BAR();
    half8 bf[4][2];
#pragma unroll
    for (int nf = 0; nf < 4; ++nf) {
      const int rn = wc * 64 + nf * 16 + fr;
#pragma unroll
      for (int ks = 0; ks < 2; ++ks) {
        const int c = (ks * 4 + fk) ^ (rn & 7);
        bf[nf][ks] = *(const half8*)&lB[p][rn * 64 + c * 8];
      }
    }
    if (t < 15) {
      STAGEA(p ^ 1, t + 1);
      STAGEB(p ^ 1, t + 1);
    }
#pragma unroll
    for (int mf = 0; mf < 4; ++mf) {
      const int r = wr * 64 + mf * 16 + fr;
      half8 ah[2], al[2];
#pragma unroll
      for (int ks = 0; ks < 2; ++ks) {
        const int kc = ks * 4 + fk;
        const int ch = kc ^ (r & 7);         // hi chunk (0..7)
        ah[ks] = *(const half8*)&lA[p][r * 128 + ch * 8];
        al[ks] = *(const half8*)&lA[p][r * 128 + (ch + 8) * 8];  // lo region
      }
      __builtin_amdgcn_s_setprio(1);
#pragma unroll
      for (int nf = 0; nf < 4; ++nf)
#pragma unroll
        for (int ks = 0; ks < 2; ++ks) {
          acc[mf][nf] = __builtin_amdgcn_mfma_f32_16x16x32_f16(
              ah[ks], bf[nf][ks], acc[mf][nf], 0, 0, 0);
          acc[mf][nf] = __builtin_amdgcn_mfma_f32_16x16x32_f16(
              al[ks], bf[nf][ks], acc[mf][nf], 0, 0, 0);
        }
      __builtin_amdgcn_s_setprio(0);
    }
  }
#undef STAGEA
#undef STAGEB

  const int cb = n0 + wc * 64 + fr;
  const int rb = m0 + wr * 64 + fk * 4;
#pragma unroll
  for (int mf = 0; mf < 4; ++mf)
#pragma unroll
    for (int nf = 0; nf < 4; ++nf) {
      const int col = cb + nf * 16;
#pragma unroll
      for (int j = 0; j < 4; ++j) {
        const int row = rb + mf * 16 + j;
        Cf[(size_t)row * 1024 + col] = acc[mf][nf][j];
      }
    }
}

// ---------------- single-pass bf16 GEMM, 2-buf, 1 barrier per K-tile ----------------
// CM 0: ctx = attn[b] @ hT[b]^T, batched, bf16 out.
// CM 1: out = sigmoid(A @ Bt^T + bias), flat M=16384, f32 out.
template <int CM>
__global__ __launch_bounds__(512) void gemm1_8ph_k(
    const u16* __restrict__ A_, const u16* __restrict__ Bt_,
    const float* __restrict__ bias, void* __restrict__ Cout) {
  __shared__ u16 lds[2][2][256 * 64];  // 131072 B
  const int bid = blockIdx.x;
  const int swz = (bid & 7) * 32 + (bid >> 3);
  int m0, n0;
  const u16 *A, *Bt;
  float* Cf = nullptr;
  u16* Cb = nullptr;
  if (CM == 0) {
    const int z = swz >> 3;
    m0 = ((swz >> 2) & 1) * 256;
    n0 = (swz & 3) * 256;
    A = A_ + (size_t)z * 512 * 1024;
    Bt = Bt_ + (size_t)z * 1024 * 1024;
    Cb = (u16*)Cout + (size_t)z * 512 * 1024;
  } else {
    m0 = (swz >> 2) * 256;
    n0 = (swz & 3) * 256;
    A = A_; Bt = Bt_;
    Cf = (float*)Cout;
  }
  const int tid = threadIdx.x;
  const int lane = tid & 63, wid = tid >> 6;
  const int wr = wid >> 2, wc = wid & 3;
  const int fr = lane & 15, fk = lane >> 4;

  f32x4 acc[8][4] = {};

#define STAGE1(pb, q, gp, rb, kt)                                              \
  {                                                                            \
    _Pragma("unroll") for (int j = 0; j < 4; ++j) {                            \
      const int slot = j * 512 + tid;                                          \
      const int r = slot >> 3;                                                 \
      const int g = (slot & 7) ^ (r & 7);                                      \
      gload16((gp) + (size_t)((rb) + r) * 1024 + (kt) * 64 + g * 8,            \
              &lds[pb][q][(j * 512 + wid * 64) * 8]);                          \
    }                                                                          \
  }

  STAGE1(0, 0, A, m0, 0);
  STAGE1(0, 1, Bt, n0, 0);

  for (int t = 0; t < 16; ++t) {
    const int p = t & 1;
    WAIT_VMN(0);
    BAR();
    short8 bfr[4][2];
#pragma unroll
    for (int nf = 0; nf < 4; ++nf) {
      const int rn = wc * 64 + nf * 16 + fr;
#pragma unroll
      for (int ks = 0; ks < 2; ++ks) {
        const int g = (ks * 4 + fk) ^ (rn & 7);
        bfr[nf][ks] = *(const short8*)&lds[p][1][rn * 64 + g * 8];
      }
    }
    if (t < 15) {
      STAGE1(p ^ 1, 0, A, m0, t + 1);
      STAGE1(p ^ 1, 1, Bt, n0, t + 1);
    }
#pragma unroll
    for (int ph = 0; ph < 4; ++ph) {
      short8 a[2][2];
#pragma unroll
      for (int i = 0; i < 2; ++i) {
        const int r = wr * 128 + (ph * 2 + i) * 16 + fr;
#pragma unroll
        for (int ks = 0; ks < 2; ++ks) {
          const int g = (ks * 4 + fk) ^ (r & 7);
          a[i][ks] = *(const short8*)&lds[p][0][r * 64 + g * 8];
        }
      }
      __builtin_amdgcn_s_setprio(1);
#pragma unroll
      for (int i = 0; i < 2; ++i)
#pragma unroll
        for (int nf = 0; nf < 4; ++nf) {
          acc[ph * 2 + i][nf] = __builtin_amdgcn_mfma_f32_16x16x32_bf16(
              a[i][0], bfr[nf][0], acc[ph * 2 + i][nf], 0, 0, 0);
          acc[ph * 2 + i][nf] = __builtin_amdgcn_mfma_f32_16x16x32_bf16(
              a[i][1], bfr[nf][1], acc[ph * 2 + i][nf], 0, 0, 0);
        }
      __builtin_amdgcn_s_setprio(0);
    }
  }
#undef STAGE1

  const int cb = n0 + wc * 64 + fr;
  const int rb = m0 + wr * 128 + fk * 4;
  if (CM == 0) {
#pragma unroll
    for (int mf = 0; mf < 8; ++mf)
#pragma unroll
      for (int nf = 0; nf < 4; ++nf) {
        const int col = cb + nf * 16;
#pragma unroll
        for (int j = 0; j < 4; ++j) {
          const int row = rb + mf * 16 + j;
          Cb[(size_t)row * 1024 + col] = f2bf(acc[mf][nf][j]);
        }
      }
  } else {
#pragma unroll
    for (int mf = 0; mf < 8; ++mf)
#pragma unroll
      for (int nf = 0; nf < 4; ++nf) {
        const int col = cb + nf * 16;
        const float bv = bias[col];
#pragma unroll
        for (int j = 0; j < 4; ++j) {
          const int row = rb + mf * 16 + j;
          const float xv = acc[mf][nf][j] + bv;
          Cf[(size_t)row * 1024 + col] = 1.0f / (1.0f + __expf(-xv));
        }
      }
  }
}

// ---------------- softmax over last dim (1024), writes compact bf16 attn ----------------
__global__ __launch_bounds__(256) void softmax_k(const float* __restrict__ S,
                                                 u16* __restrict__ Attn) {
  const float* rp = S + (size_t)blockIdx.x * 1024;
  const int tid = threadIdx.x;
  const int lane = tid & 63, wid = tid >> 6;
  const f32x4 v = ((const f32x4*)rp)[tid];
  float mx = fmaxf(fmaxf(v[0], v[1]), fmaxf(v[2], v[3]));
#pragma unroll
  for (int off = 32; off; off >>= 1) mx = fmaxf(mx, __shfl_xor(mx, off));
  __shared__ float red[4];
  __shared__ float red2[4];
  if (lane == 0) red[wid] = mx;
  __syncthreads();
  mx = fmaxf(fmaxf(red[0], red[1]), fmaxf(red[2], red[3]));
  const float e0 = __expf(v[0] - mx), e1 = __expf(v[1] - mx);
  const float e2 = __expf(v[2] - mx), e3 = __expf(v[3] - mx);
  float s = (e0 + e1) + (e2 + e3);
#pragma unroll
  for (int off = 32; off; off >>= 1) s += __shfl_xor(s, off);
  if (lane == 0) red2[wid] = s;
  __syncthreads();
  const float inv = 1.0f / (red2[0] + red2[1] + red2[2] + red2[3]);
  u16x4 o;
  o[0] = f2bf(e0 * inv); o[1] = f2bf(e1 * inv); o[2] = f2bf(e2 * inv); o[3] = f2bf(e3 * inv);
  ((u16x4*)(Attn + (size_t)blockIdx.x * 1024))[tid] = o;
}

// ---------------- launch ----------------
// Shapes: S=1024, B=32, H=1024, T=512.
//   q'  = x @ K_w            (fused f32->fp16-split convert + 2-pass fp16 GEMM; K_b dropped)
//   scr = q'[b] @ hf16[b]^T  (fp16 2-pass, BK=64, 16 boundaries)
//   attn = softmax(scr)      (compact bf16)
//   ctx = attn[b] @ hT[b]^T  (bf16, BK=64)
//   out = sigmoid(ctx @ V_w^T + V_b)
// ws (MB): hf16 0-64 (attn reuses 0-32) | hT 64-128 | qhi 128-160 (ctx reuses) |
//          qlo 160-192 | scores f32 192-256 | kwT 256-258 | vw 258-260
extern "C" void kernel_launch(void* const* d_in, const int* in_sizes, int n_in,
                              void* d_out, int out_size, void* d_ws, size_t ws_size,
                              hipStream_t stream) {
  const float* hidden = (const float*)d_in[0];
  const float* x = (const float*)d_in[1];
  // d_in[2] problem_q unused; d_in[4] K_b dropped (softmax shift invariance)
  const float* K_w = (const float*)d_in[3];
  const float* V_w = (const float*)d_in[5];
  const float* V_b = (const float*)d_in[6];

  char* ws = (char*)d_ws;
  u16* hf16 = (u16*)(ws);
  u16* hT = (u16*)(ws + 67108864);
  u16* qhi = (u16*)(ws + 134217728);
  u16* qlo = (u16*)(ws + 167772160);
  float* scoresF = (float*)(ws + 201326592);
  u16* attn = hf16;  // reuse (hf16 dead after scores)
  u16* ctx = qhi;    // reuse (q' dead after scores)
  u16* kwT = (u16*)(ws + 268435456);
  u16* vw = kwT + 1024 * 1024;
  float* out = (float*)d_out;

  // 1. hidden [S,B,H] -> fp16 [B,S,H] + transposed bf16 [B,H,S]
  cvt_hidden2_k<<<dim3(16, 8, 32), 512, 0, stream>>>(hidden, hf16, hT);
  // 2. weights: K_w transposed fp16, V_w bf16
  cvt_w_t_h_k<<<dim3(16, 16), 256, 0, stream>>>(K_w, kwT);
  cvt_f32_bf16_k<<<1024, 256, 0, stream>>>(V_w, vw, 1024L * 1024 / 4);
  // 3. q' = x @ K_w  (x f32 consumed directly; split done in-kernel)
  gemm_qp_k<<<256, 512, 0, stream>>>(x, kwT, qhi, qlo);
  // 4. scores[b] = q'[b] @ hf16[b]^T  (BK=64)
  gemm_sc_k<<<512, 512, 0, stream>>>(qhi, qlo, hf16, scoresF);
  // 5. softmax over S -> compact bf16 attn
  softmax_k<<<16384, 256, 0, stream>>>(scoresF, attn);
  // 6. ctx[b] = attn[b] @ hT[b]^T
  gemm1_8ph_k<0><<<256, 512, 0, stream>>>(attn, hT, nullptr, ctx);
  // 7. out = sigmoid(ctx @ V_w^T + V_b)
  gemm1_8ph_k<1><<<256, 512, 0, stream>>>(ctx, vw, V_b, out);
}

// Round 17
// 321.449 us; speedup vs baseline: 1.2258x; 1.0424x over previous
//
#include <hip/hip_runtime.h>

typedef unsigned short u16;
typedef __attribute__((ext_vector_type(8))) short short8;
typedef __attribute__((ext_vector_type(8))) _Float16 half8;
typedef __attribute__((ext_vector_type(4))) float f32x4;
typedef __attribute__((ext_vector_type(4))) u16 u16x4;
typedef __attribute__((ext_vector_type(4))) unsigned int u32x4;

#define DEVINL static __device__ __forceinline__

DEVINL u16 f2bf(float f) {
  unsigned u = __builtin_bit_cast(unsigned, f);
  u += 0x7fffu + ((u >> 16) & 1u);
  return (u16)(u >> 16);
}
DEVINL float bf2f(u16 h) {
  return __builtin_bit_cast(float, ((unsigned)h) << 16);
}
DEVINL u16 f2h(float f) { return __builtin_bit_cast(u16, (_Float16)f); }
DEVINL float h2f(u16 h) { return (float)__builtin_bit_cast(_Float16, h); }

// async global->LDS, 16B per lane; lds base must be wave-uniform
DEVINL void gload16(const void* g, void* l) {
  __builtin_amdgcn_global_load_lds(
      (const __attribute__((address_space(1))) void*)g,
      (__attribute__((address_space(3))) void*)l, 16, 0, 0);
}

#define BAR() asm volatile("s_barrier" ::: "memory")
#define WAIT_VMN(n) asm volatile("s_waitcnt vmcnt(" #n ")" ::: "memory")
#define WAIT_VM_LGKM0() asm volatile("s_waitcnt vmcnt(0) lgkmcnt(0)" ::: "memory")

// ---------------- converts ----------------

// hidden [S=1024,B=32,H=1024] f32 -> hf16 [B,S,H] fp16 + hT [B,H,S] bf16
__global__ __launch_bounds__(512) void cvt_hidden2_k(const float* __restrict__ hid,
                                                     u16* __restrict__ hf,
                                                     u16* __restrict__ hT) {
  __shared__ u16 tl[64][136];
  const int s0 = blockIdx.x * 64;
  const int h0 = blockIdx.y * 128;
  const int b = blockIdx.z;
  const int t = threadIdx.x;
  const int r = t >> 5;
  const int c4 = (t & 31) * 4;
#pragma unroll
  for (int it = 0; it < 4; ++it) {
    const int s = it * 16 + r;
    const f32x4 v = *(const f32x4*)(hid + ((size_t)(s0 + s) * 32 + b) * 1024 + h0 + c4);
    u16x4 of;
    const int cs = c4 ^ (it << 2);
#pragma unroll
    for (int j = 0; j < 4; ++j) {
      of[j] = f2h(v[j]);
      tl[s][cs + j] = f2bf(v[j]);
    }
    *(u16x4*)(hf + ((size_t)b * 1024 + s0 + s) * 1024 + h0 + c4) = of;
  }
  __syncthreads();
  const int h = t >> 2;
  const int sq = (t & 3) * 16;
  u16 tmp[16] __attribute__((aligned(16)));
#pragma unroll
  for (int i = 0; i < 16; ++i)
    tmp[i] = tl[sq + i][h ^ ((((sq + i) >> 4) & 3) << 2)];
  u16* dst = hT + ((size_t)b * 1024 + h0 + h) * 1024 + s0 + sq;
  *(u32x4*)(dst) = *(const u32x4*)&tmp[0];
  *(u32x4*)(dst + 8) = *(const u32x4*)&tmp[8];
}

// generic f32 -> bf16 (single)
__global__ __launch_bounds__(256) void cvt_f32_bf16_k(const float* __restrict__ in,
                                                      u16* __restrict__ out, long n4) {
  long i = (long)blockIdx.x * 256 + threadIdx.x;
  const long stride = (long)gridDim.x * 256;
  for (; i < n4; i += stride) {
    const f32x4 v = ((const f32x4*)in)[i];
    u16x4 o;
#pragma unroll
    for (int j = 0; j < 4; ++j) o[j] = f2bf(v[j]);
    ((u16x4*)out)[i] = o;
  }
}

// K_w [j=1024][h=1024] f32 -> transposed single fp16: out[h][j]
__global__ __launch_bounds__(256) void cvt_w_t_h_k(const float* __restrict__ in,
                                                   u16* __restrict__ out) {
  __shared__ float tile[64][65];
  const int bh = blockIdx.x * 64;
  const int bj = blockIdx.y * 64;
  const int t = threadIdx.x;
  const int r = t >> 4;
  const int c4 = (t & 15) * 4;
#pragma unroll
  for (int it = 0; it < 4; ++it) {
    const int row = it * 16 + r;
    const f32x4 v = *(const f32x4*)(in + (size_t)(bj + row) * 1024 + bh + c4);
#pragma unroll
    for (int j = 0; j < 4; ++j) tile[c4 + j][row] = v[j];
  }
  __syncthreads();
#pragma unroll
  for (int it = 0; it < 4; ++it) {
    const int hrow = it * 16 + r;
    u16x4 of;
#pragma unroll
    for (int j = 0; j < 4; ++j) of[j] = f2h(tile[hrow][c4 + j]);
    *(u16x4*)(out + (size_t)(bh + hrow) * 1024 + bj + c4) = of;
  }
}

// ---------------- qp: fused-convert 2-pass fp16 GEMM (r14, 93us) ----------------
__global__ __launch_bounds__(512) void gemm_qp_k(
    const float* __restrict__ X, const u16* __restrict__ Bm,
    u16* __restrict__ Chi, u16* __restrict__ Clo) {
  __shared__ u16 lA[2][256 * 64];  // 64 KiB
  __shared__ u16 lB[2][256 * 32];  // 32 KiB
  const int bid = blockIdx.x;
  const int swz = (bid & 7) * 32 + (bid >> 3);
  const int m0 = (swz >> 2) * 256;
  const int n0 = (swz & 3) * 256;
  const int tid = threadIdx.x;
  const int lane = tid & 63, wid = tid >> 6;
  const int wr = wid >> 2, wc = wid & 3;
  const int fr = lane & 15, fk = lane >> 4;

  f32x4 acc[8][4] = {};

#define STAGEAF(pb, kt)                                                        \
  {                                                                            \
    _Pragma("unroll") for (int j = 0; j < 2; ++j) {                            \
      const int ps = j * 512 + tid;                                            \
      const int r = ps >> 2, q = ps & 3;                                       \
      const float* src = X + (size_t)(m0 + r) * 1024 + (kt) * 32 + q * 8;      \
      const f32x4 v0 = *(const f32x4*)src;                                     \
      const f32x4 v1 = *(const f32x4*)(src + 4);                               \
      short8 hs, ls;                                                           \
      _Pragma("unroll") for (int e = 0; e < 4; ++e) {                          \
        const u16 a0 = f2h(v0[e]);                                             \
        const u16 a1 = f2h(v1[e]);                                             \
        hs[e] = (short)a0;                                                     \
        hs[e + 4] = (short)a1;                                                 \
        ls[e] = (short)f2h(v0[e] - h2f(a0));                                   \
        ls[e + 4] = (short)f2h(v1[e] - h2f(a1));                               \
      }                                                                        \
      const int c = q ^ (r & 7);                                               \
      *(short8*)&lA[pb][r * 64 + c * 8] = hs;                                  \
      *(short8*)&lA[pb][r * 64 + (c ^ 4) * 8] = ls;                            \
    }                                                                          \
  }
#define STAGEB(pb, kt)                                                         \
  {                                                                            \
    _Pragma("unroll") for (int j = 0; j < 2; ++j) {                            \
      const int slot = j * 512 + tid;                                          \
      const int r = slot >> 2;                                                 \
      const int g = (slot & 3) ^ ((r >> 1) & 3);                               \
      gload16(Bm + (size_t)(n0 + r) * 1024 + (kt) * 32 + g * 8,                \
              &lB[pb][(j * 512 + wid * 64) * 8]);                              \
    }                                                                          \
  }

  STAGEAF(0, 0);
  STAGEB(0, 0);

  for (int t = 0; t < 32; ++t) {
    const int p = t & 1;
    WAIT_VM_LGKM0();
    BAR();
    half8 bf[4];
#pragma unroll
    for (int nf = 0; nf < 4; ++nf) {
      const int rn = wc * 64 + nf * 16 + fr;
      const int cn = fk ^ ((rn >> 1) & 3);
      bf[nf] = *(const half8*)&lB[p][rn * 32 + cn * 8];
    }
    if (t < 31) {
      STAGEB(p ^ 1, t + 1);
      STAGEAF(p ^ 1, t + 1);
    }
#pragma unroll
    for (int ph = 0; ph < 4; ++ph) {
      half8 ah[2], al[2];
#pragma unroll
      for (int i = 0; i < 2; ++i) {
        const int r = wr * 128 + (ph * 2 + i) * 16 + fr;
        const int ch = fk ^ (r & 7);
        ah[i] = *(const half8*)&lA[p][r * 64 + ch * 8];
        al[i] = *(const half8*)&lA[p][r * 64 + (ch ^ 4) * 8];
      }
      __builtin_amdgcn_s_setprio(1);
#pragma unroll
      for (int i = 0; i < 2; ++i)
#pragma unroll
        for (int nf = 0; nf < 4; ++nf) {
          acc[ph * 2 + i][nf] =
              __builtin_amdgcn_mfma_f32_16x16x32_f16(ah[i], bf[nf], acc[ph * 2 + i][nf], 0, 0, 0);
          acc[ph * 2 + i][nf] =
              __builtin_amdgcn_mfma_f32_16x16x32_f16(al[i], bf[nf], acc[ph * 2 + i][nf], 0, 0, 0);
        }
      __builtin_amdgcn_s_setprio(0);
    }
  }
#undef STAGEAF
#undef STAGEB

  const int cb = n0 + wc * 64 + fr;
  const int rb = m0 + wr * 128 + fk * 4;
#pragma unroll
  for (int mf = 0; mf < 8; ++mf)
#pragma unroll
    for (int nf = 0; nf < 4; ++nf) {
      const int col = cb + nf * 16;
#pragma unroll
      for (int j = 0; j < 4; ++j) {
        const int row = rb + mf * 16 + j;
        const float kv = acc[mf][nf][j];
        const u16 hi = f2h(kv);
        Chi[(size_t)row * 1024 + col] = hi;
        Clo[(size_t)row * 1024 + col] = f2h(kv - h2f(hi));
      }
    }
}

// ---------------- sc_fused: scores + softmax -> compact bf16 attn ----------------
// Per block: 64 q-rows x FULL S (N=1024), K=1024, BK=32, 2-buf, minimal sync.
// 8 waves as 1x8 (wave cols = wid*128), wave tile 64x128, acc[4][8].
// A pair fp16 (rows 128B, chunk g=c^(r&7): g<4 hi else lo); B fp16 [1024][32]
// (rows 64B, chunk g=c^((r>>1)&3)). Epilogue: block-local softmax over S
// (shfl over 16-lane col group + cross-wave LDS reduce), bf16 attn out.
// Grid 256 = 32 batches x 8 strips, XCD-grouped (4 batches/XCD).
__global__ __launch_bounds__(512) void gemm_sc_fused_k(
    const u16* __restrict__ Qh_, const u16* __restrict__ Ql_,
    const u16* __restrict__ Hf_, u16* __restrict__ Attn) {
  __shared__ u16 lA[2][64 * 64];    // 16 KiB
  __shared__ u16 lB[2][1024 * 32];  // 128 KiB
  __shared__ float red[8][64];
  __shared__ float grow[64];
  const int bid = blockIdx.x;
  const int swz = (bid & 7) * 32 + (bid >> 3);  // bijective on 256
  const int z = swz >> 3;
  const int m0 = (swz & 7) * 64;
  const u16* Ah = Qh_ + (size_t)z * 512 * 1024 + (size_t)m0 * 1024;
  const u16* Al = Ql_ + (size_t)z * 512 * 1024 + (size_t)m0 * 1024;
  const u16* Bm = Hf_ + (size_t)z * 1024 * 1024;
  u16* Ao = Attn + (size_t)z * 512 * 1024 + (size_t)m0 * 1024;
  const int tid = threadIdx.x;
  const int lane = tid & 63, wid = tid >> 6;
  const int fr = lane & 15, fk = lane >> 4;

  f32x4 acc[4][8] = {};

  // A: 64 rows x 8 chunks = 512 slots, 1/thread
#define STAGEA(pb, kt)                                                         \
  {                                                                            \
    const int r = tid >> 3;                                                    \
    const int g = (tid & 7) ^ (r & 7);                                         \
    const u16* src = (g < 4) ? Ah : Al;                                        \
    gload16(src + (size_t)r * 1024 + (kt) * 32 + (g & 3) * 8,                  \
            &lA[pb][(wid * 64) * 8]);                                          \
  }
  // B: 1024 rows x 4 chunks = 4096 slots, 8/thread
#define STAGEB(pb, kt)                                                         \
  {                                                                            \
    _Pragma("unroll") for (int j = 0; j < 8; ++j) {                            \
      const int slot = j * 512 + tid;                                          \
      const int r = slot >> 2;                                                 \
      const int g = (slot & 3) ^ ((r >> 1) & 3);                               \
      gload16(Bm + (size_t)r * 1024 + (kt) * 32 + g * 8,                       \
              &lB[pb][(j * 512 + wid * 64) * 8]);                              \
    }                                                                          \
  }

  STAGEA(0, 0);
  STAGEB(0, 0);

  for (int t = 0; t < 32; ++t) {
    const int p = t & 1;
    WAIT_VMN(0);
    BAR();
    half8 bf[8];
#pragma unroll
    for (int nf = 0; nf < 8; ++nf) {
      const int rn = wid * 128 + nf * 16 + fr;
      const int cn = fk ^ ((rn >> 1) & 3);
      bf[nf] = *(const half8*)&lB[p][rn * 32 + cn * 8];
    }
    if (t < 31) {
      STAGEA(p ^ 1, t + 1);
      STAGEB(p ^ 1, t + 1);
    }
#pragma unroll
    for (int mf = 0; mf < 4; ++mf) {
      const int r = mf * 16 + fr;
      const int ch = fk ^ (r & 7);
      const half8 ah = *(const half8*)&lA[p][r * 64 + ch * 8];
      const half8 al = *(const half8*)&lA[p][r * 64 + (ch ^ 4) * 8];
      __builtin_amdgcn_s_setprio(1);
#pragma unroll
      for (int nf = 0; nf < 8; ++nf) {
        acc[mf][nf] = __builtin_amdgcn_mfma_f32_16x16x32_f16(ah, bf[nf], acc[mf][nf], 0, 0, 0);
        acc[mf][nf] = __builtin_amdgcn_mfma_f32_16x16x32_f16(al, bf[nf], acc[mf][nf], 0, 0, 0);
      }
      __builtin_amdgcn_s_setprio(0);
    }
  }
#undef STAGEA
#undef STAGEB

  // ---- softmax epilogue (rows local 0..63: lr = mf*16 + fk*4 + j) ----
  // 1. per-thread row max over nf, then reduce across fr (16-lane col group)
  float m16[4][4];
#pragma unroll
  for (int mf = 0; mf < 4; ++mf)
#pragma unroll
    for (int j = 0; j < 4; ++j) {
      float m = acc[mf][0][j];
#pragma unroll
      for (int nf = 1; nf < 8; ++nf) m = fmaxf(m, acc[mf][nf][j]);
#pragma unroll
      for (int off = 1; off < 16; off <<= 1) m = fmaxf(m, __shfl_xor(m, off));
      m16[mf][j] = m;
    }
  if (fr == 0) {
#pragma unroll
    for (int mf = 0; mf < 4; ++mf)
#pragma unroll
      for (int j = 0; j < 4; ++j) red[wid][mf * 16 + fk * 4 + j] = m16[mf][j];
  }
  __syncthreads();
  if (wid == 0 && lane < 64) {
    float g = red[0][lane];
#pragma unroll
    for (int w = 1; w < 8; ++w) g = fmaxf(g, red[w][lane]);
    grow[lane] = g;
  }
  __syncthreads();
  // 2. p = exp(s - gmax); per-row sum
#pragma unroll
  for (int mf = 0; mf < 4; ++mf)
#pragma unroll
    for (int j = 0; j < 4; ++j) {
      const float gm = grow[mf * 16 + fk * 4 + j];
      float s = 0.f;
#pragma unroll
      for (int nf = 0; nf < 8; ++nf) {
        const float e = __expf(acc[mf][nf][j] - gm);
        acc[mf][nf][j] = e;
        s += e;
      }
#pragma unroll
      for (int off = 1; off < 16; off <<= 1) s += __shfl_xor(s, off);
      m16[mf][j] = s;
    }
  __syncthreads();  // grow reads done before overwrite of red
  if (fr == 0) {
#pragma unroll
    for (int mf = 0; mf < 4; ++mf)
#pragma unroll
      for (int j = 0; j < 4; ++j) red[wid][mf * 16 + fk * 4 + j] = m16[mf][j];
  }
  __syncthreads();
  if (wid == 0 && lane < 64) {
    float g = red[0][lane];
#pragma unroll
    for (int w = 1; w < 8; ++w) g += red[w][lane];
    grow[lane] = 1.0f / g;
  }
  __syncthreads();
  // 3. write attn = bf16(p * inv)
#pragma unroll
  for (int mf = 0; mf < 4; ++mf)
#pragma unroll
    for (int j = 0; j < 4; ++j) {
      const int lr = mf * 16 + fk * 4 + j;
      const float inv = grow[lr];
      u16* rowp = Ao + (size_t)lr * 1024;
#pragma unroll
      for (int nf = 0; nf < 8; ++nf)
        rowp[wid * 128 + nf * 16 + fr] = f2bf(acc[mf][nf][j] * inv);
    }
}

// ---------------- single-pass bf16 GEMM, 2-buf, 1 barrier per K-tile ----------------
// CM 0: ctx = attn[b] @ hT[b]^T, batched, bf16 out.
// CM 1: out = sigmoid(A @ Bt^T + bias), flat M=16384, f32 out.
template <int CM>
__global__ __launch_bounds__(512) void gemm1_8ph_k(
    const u16* __restrict__ A_, const u16* __restrict__ Bt_,
    const float* __restrict__ bias, void* __restrict__ Cout) {
  __shared__ u16 lds[2][2][256 * 64];  // 131072 B
  const int bid = blockIdx.x;
  const int swz = (bid & 7) * 32 + (bid >> 3);
  int m0, n0;
  const u16 *A, *Bt;
  float* Cf = nullptr;
  u16* Cb = nullptr;
  if (CM == 0) {
    const int z = swz >> 3;
    m0 = ((swz >> 2) & 1) * 256;
    n0 = (swz & 3) * 256;
    A = A_ + (size_t)z * 512 * 1024;
    Bt = Bt_ + (size_t)z * 1024 * 1024;
    Cb = (u16*)Cout + (size_t)z * 512 * 1024;
  } else {
    m0 = (swz >> 2) * 256;
    n0 = (swz & 3) * 256;
    A = A_; Bt = Bt_;
    Cf = (float*)Cout;
  }
  const int tid = threadIdx.x;
  const int lane = tid & 63, wid = tid >> 6;
  const int wr = wid >> 2, wc = wid & 3;
  const int fr = lane & 15, fk = lane >> 4;

  f32x4 acc[8][4] = {};

#define STAGE1(pb, q, gp, rb, kt)                                              \
  {                                                                            \
    _Pragma("unroll") for (int j = 0; j < 4; ++j) {                            \
      const int slot = j * 512 + tid;                                          \
      const int r = slot >> 3;                                                 \
      const int g = (slot & 7) ^ (r & 7);                                      \
      gload16((gp) + (size_t)((rb) + r) * 1024 + (kt) * 64 + g * 8,            \
              &lds[pb][q][(j * 512 + wid * 64) * 8]);                          \
    }                                                                          \
  }

  STAGE1(0, 0, A, m0, 0);
  STAGE1(0, 1, Bt, n0, 0);

  for (int t = 0; t < 16; ++t) {
    const int p = t & 1;
    WAIT_VMN(0);
    BAR();
    short8 bfr[4][2];
#pragma unroll
    for (int nf = 0; nf < 4; ++nf) {
      const int rn = wc * 64 + nf * 16 + fr;
#pragma unroll
      for (int ks = 0; ks < 2; ++ks) {
        const int g = (ks * 4 + fk) ^ (rn & 7);
        bfr[nf][ks] = *(const short8*)&lds[p][1][rn * 64 + g * 8];
      }
    }
    if (t < 15) {
      STAGE1(p ^ 1, 0, A, m0, t + 1);
      STAGE1(p ^ 1, 1, Bt, n0, t + 1);
    }
#pragma unroll
    for (int ph = 0; ph < 4; ++ph) {
      short8 a[2][2];
#pragma unroll
      for (int i = 0; i < 2; ++i) {
        const int r = wr * 128 + (ph * 2 + i) * 16 + fr;
#pragma unroll
        for (int ks = 0; ks < 2; ++ks) {
          const int g = (ks * 4 + fk) ^ (r & 7);
          a[i][ks] = *(const short8*)&lds[p][0][r * 64 + g * 8];
        }
      }
      __builtin_amdgcn_s_setprio(1);
#pragma unroll
      for (int i = 0; i < 2; ++i)
#pragma unroll
        for (int nf = 0; nf < 4; ++nf) {
          acc[ph * 2 + i][nf] = __builtin_amdgcn_mfma_f32_16x16x32_bf16(
              a[i][0], bfr[nf][0], acc[ph * 2 + i][nf], 0, 0, 0);
          acc[ph * 2 + i][nf] = __builtin_amdgcn_mfma_f32_16x16x32_bf16(
              a[i][1], bfr[nf][1], acc[ph * 2 + i][nf], 0, 0, 0);
        }
      __builtin_amdgcn_s_setprio(0);
    }
  }
#undef STAGE1

  const int cb = n0 + wc * 64 + fr;
  const int rb = m0 + wr * 128 + fk * 4;
  if (CM == 0) {
#pragma unroll
    for (int mf = 0; mf < 8; ++mf)
#pragma unroll
      for (int nf = 0; nf < 4; ++nf) {
        const int col = cb + nf * 16;
#pragma unroll
        for (int j = 0; j < 4; ++j) {
          const int row = rb + mf * 16 + j;
          Cb[(size_t)row * 1024 + col] = f2bf(acc[mf][nf][j]);
        }
      }
  } else {
#pragma unroll
    for (int mf = 0; mf < 8; ++mf)
#pragma unroll
      for (int nf = 0; nf < 4; ++nf) {
        const int col = cb + nf * 16;
        const float bv = bias[col];
#pragma unroll
        for (int j = 0; j < 4; ++j) {
          const int row = rb + mf * 16 + j;
          const float xv = acc[mf][nf][j] + bv;
          Cf[(size_t)row * 1024 + col] = 1.0f / (1.0f + __expf(-xv));
        }
      }
  }
}

// ---------------- launch ----------------
// Shapes: S=1024, B=32, H=1024, T=512.
//   q'  = x @ K_w              (fused f32->fp16-split convert + 2-pass fp16 GEMM)
//   attn = softmax(q' @ h^T)   (sc_fused: full-S blocks, block-local softmax, bf16 out)
//   ctx = attn[b] @ hT[b]^T    (bf16, 2-buf)
//   out = sigmoid(ctx @ V_w^T + V_b)
// ws (MB): hf16 0-64 | hT 64-128 | qhi 128-160 (ctx reuses) | qlo 160-192 |
//          attn bf16 192-224 | kwT 256-258 | vw 258-260
extern "C" void kernel_launch(void* const* d_in, const int* in_sizes, int n_in,
                              void* d_out, int out_size, void* d_ws, size_t ws_size,
                              hipStream_t stream) {
  const float* hidden = (const float*)d_in[0];
  const float* x = (const float*)d_in[1];
  // d_in[2] problem_q unused; d_in[4] K_b dropped (softmax shift invariance)
  const float* K_w = (const float*)d_in[3];
  const float* V_w = (const float*)d_in[5];
  const float* V_b = (const float*)d_in[6];

  char* ws = (char*)d_ws;
  u16* hf16 = (u16*)(ws);
  u16* hT = (u16*)(ws + 67108864);
  u16* qhi = (u16*)(ws + 134217728);
  u16* qlo = (u16*)(ws + 167772160);
  u16* attn = (u16*)(ws + 201326592);  // own region: live with hf16 simultaneously
  u16* ctx = qhi;                       // reuse (q' dead after sc_fused)
  u16* kwT = (u16*)(ws + 268435456);
  u16* vw = kwT + 1024 * 1024;
  float* out = (float*)d_out;

  // 1. hidden [S,B,H] -> fp16 [B,S,H] + transposed bf16 [B,H,S]
  cvt_hidden2_k<<<dim3(16, 8, 32), 512, 0, stream>>>(hidden, hf16, hT);
  // 2. weights: K_w transposed fp16, V_w bf16
  cvt_w_t_h_k<<<dim3(16, 16), 256, 0, stream>>>(K_w, kwT);
  cvt_f32_bf16_k<<<1024, 256, 0, stream>>>(V_w, vw, 1024L * 1024 / 4);
  // 3. q' = x @ K_w  (x f32 consumed directly; split done in-kernel)
  gemm_qp_k<<<256, 512, 0, stream>>>(x, kwT, qhi, qlo);
  // 4. attn = softmax(q'[b] @ hf16[b]^T)  (fused, no scores round-trip)
  gemm_sc_fused_k<<<256, 512, 0, stream>>>(qhi, qlo, hf16, attn);
  // 5. ctx[b] = attn[b] @ hT[b]^T
  gemm1_8ph_k<0><<<256, 512, 0, stream>>>(attn, hT, nullptr, ctx);
  // 6. out = sigmoid(ctx @ V_w^T + V_b)
  gemm1_8ph_k<1><<<256, 512, 0, stream>>>(ctx, vw, V_b, out);
}